// Round 9
// baseline (162.536 us; speedup 1.0000x reference)
//
#include <hip/hip_runtime.h>
#include <hip/hip_cooperative_groups.h>

namespace cg = cooperative_groups;

#define BB 32
#define PP 8000
#define GG 100
#define PT 8100            // P + G
#define PT4 2025           // PT/4 uint4 per image (8100 % 4 == 0)
#define NSEL 512
#define POSCAP 128
#define OFF_LAB 65536      // 32*512*4
#define OFF_REG 81920      // OFF_LAB + 32*512
#define NTHR 1024
#define NWAVE 16
#define SPAN 512           // contiguous span per wave (16*512 >= 8100)
#define HB 4096            // histogram bins (top 12 of 23 key bits)
#define GCAP 512           // gather buffer cap per group
#define NBLK 256           // cooperative grid: 1 block per CU

__device__ __forceinline__ unsigned rotl32(unsigned x, int r) {
  return (x << r) | (x >> (32 - r));
}

// Threefry-2x32, 20 rounds. JAX partitionable 32-bit stream for key(42):
// counter i (uint64) -> x0 = hi(i)=0, x1 = lo(i)=i; key=(0,42); bits = out0^out1
__device__ __forceinline__ unsigned threefry_bits(unsigned ctr) {
  const unsigned k0 = 0u, k1 = 42u;
  const unsigned k2 = k0 ^ k1 ^ 0x1BD11BDAu;
  unsigned x0 = 0u + k0;
  unsigned x1 = ctr + k1;
#define TF4(a,b,c,d) \
  x0 += x1; x1 = rotl32(x1,(a)); x1 ^= x0; \
  x0 += x1; x1 = rotl32(x1,(b)); x1 ^= x0; \
  x0 += x1; x1 = rotl32(x1,(c)); x1 ^= x0; \
  x0 += x1; x1 = rotl32(x1,(d)); x1 ^= x0;
  TF4(13,15,26, 6)  x0 += k1; x1 += k2 + 1u;
  TF4(17,29,16,24)  x0 += k2; x1 += k0 + 2u;
  TF4(13,15,26, 6)  x0 += k0; x1 += k1 + 3u;
  TF4(17,29,16,24)  x0 += k1; x1 += k2 + 4u;
  TF4(13,15,26, 6)  x0 += k2; x1 += k0 + 5u;
#undef TF4
  return x0 ^ x1;
}

// Single cooperative kernel. Phase 1: all 256 blocks label (one 1024-chunk of
// one image each). grid.sync. Phase 2: blocks 0..31 select (R8 logic).
__global__ __launch_bounds__(NTHR) void roiheads_coop(
    const float* __restrict__ proposals,
    const float* __restrict__ gt_boxes,
    const int*   __restrict__ gt_labels,
    unsigned*    __restrict__ packed,
    unsigned char* __restrict__ midxv,
    float*       __restrict__ out)
{
  const int tid = threadIdx.x;
  const int lane = tid & 63;
  const int wid = tid >> 6;

  __shared__ float4  sgq[GG];
  __shared__ float   sarea[GG];
  __shared__ int     slab[GG];
  __shared__ __align__(16) unsigned sp[PT];
  __shared__ unsigned hist[HB];        // pos count low16 | neg count high16
  __shared__ unsigned waveTot[NWAVE];
  __shared__ unsigned wHard[NWAVE], wTP[NWAVE], wTN[NWAVE];
  __shared__ unsigned gbufP[GCAP], gbufN[GCAP];
  __shared__ unsigned sBin[2], sAbove[2], sTheta[2], sM[2], sCnt[2];

  // ================= phase 1: label =================
  {
    const int b = blockIdx.x >> 3;     // image
    const int c = blockIdx.x & 7;      // chunk
    if (tid < GG) {
      float4 q = ((const float4*)gt_boxes)[(size_t)b * GG + tid];
      sgq[tid] = q;
      sarea[tid] = (q.z - q.x) * (q.w - q.y);   // same op order as reference
      slab[tid] = gt_labels[b * GG + tid];
    }
    __syncthreads();

    const int t = c * NTHR + tid;
    if (t < PT) {
      float4 p = (t < PP) ? ((const float4*)proposals)[(size_t)b * PP + t]
                          : ((const float4*)gt_boxes)[(size_t)b * GG + (t - PP)];
      float area_p = (p.z - p.x) * (p.w - p.y);
      asm volatile("" : "+v"(area_p));           // block FMA contraction into sum

      float best = -1.0f;
      int bidx = 0;
      for (int g = 0; g < GG; ++g) {
        float4 q = sgq[g];
        float w = fminf(q.z, p.z) - fmaxf(q.x, p.x);
        float h = fminf(q.w, p.w) - fmaxf(q.y, p.y);
        w = fmaxf(w, 0.0f);
        h = fmaxf(h, 0.0f);
        float inter = w * h;
        asm volatile("" : "+v"(inter));          // block FMA contraction into union
        float uni = (sarea[g] + area_p) - inter;
        float iou = inter / uni;
        if (iou > best) { best = iou; bidx = g; }  // first-max == jnp argmax
      }

      int cls, m;
      if (best < 0.5f) { cls = 0; m = 0; }
      else             { cls = slab[bidx]; m = bidx; }

      unsigned bits = threefry_bits((unsigned)(b * PT + t));
      packed[(size_t)b * PT + t] = (bits >> 9) | ((unsigned)cls << 24);
      midxv[(size_t)b * PT + t] = (unsigned char)m;
    }
  }

  __threadfence();                     // device-scope release of packed/midxv
  cg::this_grid().sync();
  if (blockIdx.x >= BB) return;

  // ================= phase 2: select =================
  const int b = blockIdx.x;
  const unsigned long long laneLT = (lane == 63) ? 0x7FFFFFFFFFFFFFFFull
                                                 : ((1ull << lane) - 1ull);

  // 1: zero histogram
#pragma unroll
  for (int i = 0; i < HB / NTHR; ++i) hist[tid + i * NTHR] = 0u;
  __syncthreads();

  // 2: load keys as uint4 + histogram from registers (one fused pass)
  {
    const uint4* pk4 = (const uint4*)(packed + (size_t)b * PT);
    for (int i = tid; i < PT4; i += NTHR) {
      uint4 v = pk4[i];
      ((uint4*)sp)[i] = v;
#define H1(x) atomicAdd(&hist[((x) & 0x7FFFFFu) >> 11], ((x) >> 24) >= 1u ? 1u : 0x10000u)
      H1(v.x); H1(v.y); H1(v.z); H1(v.w);
#undef H1
    }
  }
  __syncthreads();

  // 3: block suffix-scan over per-thread 4-bin sums (packed)
  const int BPT = HB / NTHR;           // 4 bins per thread
  unsigned local = 0;
#pragma unroll
  for (int j = 0; j < BPT; ++j) local += hist[tid * BPT + j];
  unsigned suf = local;
  for (int d = 1; d < 64; d <<= 1) {
    unsigned o = __shfl_down(suf, d, 64);
    if (lane + d < 64) suf += o;
  }
  if (lane == 0) waveTot[wid] = suf;   // whole-wave sum
  __syncthreads();

  // 4: totals, caps, locate threshold bins; zero gather counters
  unsigned totAll = 0, waveAfter = 0;
#pragma unroll
  for (int w = 0; w < NWAVE; ++w) { unsigned x = waveTot[w]; totAll += x; if (w > wid) waveAfter += x; }
  unsigned num_pos = totAll & 0xFFFFu, num_neg = totAll >> 16;
  bool allP = (num_pos <= POSCAP);
  unsigned capP = allP ? num_pos : POSCAP;
  unsigned Kneg = NSEL - capP;
  bool allN = (num_neg <= Kneg);
  unsigned sumAfter = waveAfter + (suf - local);  // threads strictly after me
  {
    unsigned aP = sumAfter & 0xFFFFu, aN = sumAfter >> 16;
#pragma unroll
    for (int j = BPT - 1; j >= 0; --j) {
      unsigned hc = hist[tid * BPT + j];
      unsigned hp = hc & 0xFFFFu, hn = hc >> 16;
      if (!allP && aP < POSCAP && aP + hp >= POSCAP) { sBin[0] = tid * BPT + j; sAbove[0] = aP; }
      if (!allN && aN < Kneg   && aN + hn >= Kneg)   { sBin[1] = tid * BPT + j; sAbove[1] = aN; }
      aP += hp; aN += hn;
    }
  }
  if (tid < 2) sCnt[tid] = 0u;
  __syncthreads();

  // 5: gather members of the threshold bins
  unsigned binP = sBin[0], binN = sBin[1];
  for (int t = tid; t < PT; t += NTHR) {
    unsigned v = sp[t];
    unsigned key = v & 0x7FFFFFu;
    bool isP = (v >> 24) >= 1u;
    if (!allP && isP && (key >> 11) == binP) {
      unsigned i = atomicAdd(&sCnt[0], 1u);
      if (i < GCAP) gbufP[i] = key;
    }
    if (!allN && !isP && (key >> 11) == binN) {
      unsigned i = atomicAdd(&sCnt[1], 1u);
      if (i < GCAP) gbufN[i] = key;
    }
  }
  __syncthreads();

  // 6: exact in-bin rank resolve (wave 0: pos, wave 1: neg)
  if (wid == 0 && !allP) {
    int n = min((int)sCnt[0], GCAP);
    unsigned above = sAbove[0];
    unsigned r = POSCAP - above;       // 1-indexed rank within bin
    for (int i = lane; i < n; i += 64) {
      unsigned ki = gbufP[i];
      unsigned gt = 0, ge = 0;
      for (int j = 0; j < n; ++j) { unsigned kj = gbufP[j]; gt += (kj > ki); ge += (kj >= ki); }
      if (gt < r && ge >= r) { sTheta[0] = ki; sM[0] = POSCAP - (above + gt); }
    }
  }
  if (wid == 1 && !allN) {
    int n = min((int)sCnt[1], GCAP);
    unsigned above = sAbove[1];
    unsigned r = Kneg - above;
    for (int i = lane; i < n; i += 64) {
      unsigned ki = gbufN[i];
      unsigned gt = 0, ge = 0;
      for (int j = 0; j < n; ++j) { unsigned kj = gbufN[j]; gt += (kj > ki); ge += (kj >= ki); }
      if (gt < r && ge >= r) { sTheta[1] = ki; sM[1] = Kneg - (above + gt); }
    }
  }
  __syncthreads();

  unsigned thetaP = allP ? 0u : sTheta[0];
  unsigned mP     = allP ? 0u : sM[0];
  unsigned thetaN = allN ? 0u : sTheta[1];
  unsigned mN     = allN ? 0u : sM[1];

  // 7: pass 1 — per-wave tie/hard counts over its contiguous span (stride-1)
  const int s0 = wid * SPAN;
  unsigned hardCnt = 0, tpCnt = 0, tnCnt = 0;
#pragma unroll
  for (int step = 0; step < SPAN / 64; ++step) {
    int t = s0 + step * 64 + lane;
    bool hard = false, tp = false, tn = false;
    if (t < PT) {
      unsigned v = sp[t];
      unsigned key = v & 0x7FFFFFu;
      if ((v >> 24) >= 1u) {
        if (allP || key > thetaP) hard = true;
        else if (key == thetaP)   tp = true;
      } else {
        if (allN || key > thetaN) hard = true;
        else if (key == thetaN)   tn = true;
      }
    }
    hardCnt += __popcll(__ballot(hard));
    tpCnt   += __popcll(__ballot(tp));
    tnCnt   += __popcll(__ballot(tn));
  }
  if (lane == 0) { wHard[wid] = hardCnt; wTP[wid] = tpCnt; wTN[wid] = tnCnt; }
  __syncthreads();

  // 8: per-wave bases (ties taken in global index order -> analytic)
  unsigned tieBaseP = 0, tieBaseN = 0, posBase = 0;
  {
    unsigned tb = 0, nb = 0;
#pragma unroll
    for (int w = 0; w < NWAVE; ++w) {
      if (w == wid) { tieBaseP = tb; tieBaseN = nb; break; }
      unsigned takeP = (mP > tb) ? min(mP - tb, wTP[w]) : 0u;
      unsigned takeN = (mN > nb) ? min(mN - nb, wTN[w]) : 0u;
      posBase += wHard[w] + takeP + takeN;
      tb += wTP[w]; nb += wTN[w];
    }
  }

  // 9: pass 2 — decide + write (ballot ranks, stable index order)
  unsigned runP = tieBaseP, runN = tieBaseN, posRun = posBase;
#pragma unroll
  for (int step = 0; step < SPAN / 64; ++step) {
    int t = s0 + step * 64 + lane;
    bool hard = false, tp = false, tn = false;
    unsigned cls = 0;
    if (t < PT) {
      unsigned v = sp[t];
      unsigned key = v & 0x7FFFFFu;
      cls = v >> 24;
      if (cls >= 1u) {
        if (allP || key > thetaP) hard = true;
        else if (key == thetaP)   tp = true;
      } else {
        if (allN || key > thetaN) hard = true;
        else if (key == thetaN)   tn = true;
      }
    }
    unsigned long long mtp = __ballot(tp);
    unsigned long long mtn = __ballot(tn);
    bool sel = hard
             | (tp && (runP + __popcll(mtp & laneLT)) < mP)
             | (tn && (runN + __popcll(mtn & laneLT)) < mN);
    unsigned long long msel = __ballot(sel);

    if (sel) {
      unsigned pos = posRun + __popcll(msel & laneLT);
      float4 p = (t < PP) ? ((const float4*)proposals)[(size_t)b * PP + t]
                          : ((const float4*)gt_boxes)[(size_t)b * GG + (t - PP)];
      int m = midxv[(size_t)b * PT + t];
      float4 gq = ((const float4*)gt_boxes)[(size_t)b * GG + m];

      size_t o1 = (size_t)b * NSEL + pos;
      out[o1 * 4 + 0] = p.x;
      out[o1 * 4 + 1] = p.y;
      out[o1 * 4 + 2] = p.z;
      out[o1 * 4 + 3] = p.w;
      out[OFF_LAB + o1] = (float)cls;

      float pw = p.z - p.x, ph = p.w - p.y;
      float px = p.x + 0.5f * pw, py = p.y + 0.5f * ph;
      float gw = gq.z - gq.x, gh = gq.w - gq.y;
      float gx = gq.x + 0.5f * gw, gy = gq.y + 0.5f * gh;
      size_t o2 = OFF_REG + o1 * 4;
      out[o2 + 0] = 10.0f * (gx - px) / pw;
      out[o2 + 1] = 10.0f * (gy - py) / ph;
      out[o2 + 2] = 5.0f * logf(gw / pw);
      out[o2 + 3] = 5.0f * logf(gh / ph);
    }

    runP += __popcll(mtp);
    runN += __popcll(mtn);
    posRun += __popcll(msel);
  }
}

extern "C" void kernel_launch(void* const* d_in, const int* in_sizes, int n_in,
                              void* d_out, int out_size, void* d_ws, size_t ws_size,
                              hipStream_t stream) {
  const float* proposals = (const float*)d_in[0];
  const float* gt_boxes  = (const float*)d_in[1];
  const int*   gt_labels = (const int*)d_in[2];
  float* out = (float*)d_out;

  unsigned* packed = (unsigned*)d_ws;
  unsigned char* midxv = (unsigned char*)d_ws + (size_t)BB * PT * sizeof(unsigned);

  void* args[6] = { (void*)&proposals, (void*)&gt_boxes, (void*)&gt_labels,
                    (void*)&packed, (void*)&midxv, (void*)&out };
  hipLaunchCooperativeKernel((const void*)roiheads_coop, dim3(NBLK), dim3(NTHR),
                             args, 0, stream);
}

// Round 10
// 86.268 us; speedup vs baseline: 1.8841x; 1.8841x over previous
//
#include <hip/hip_runtime.h>

#define BB 32
#define PP 8000
#define GG 100
#define PT 8100            // P + G
#define PT4 2025           // PT/4 uint4 per image
#define NSEL 512
#define POSCAP 128
#define OFF_LAB 65536      // 32*512*4
#define OFF_REG 81920      // OFF_LAB + 32*512
#define NTHR 1024
#define NWAVE 16
#define SPAN 512           // contiguous span per wave (16*512 >= 8100)
#define HB 4096            // histogram bins (top 12 of 23 key bits)
#define GCAP 512           // gather buffer cap per group
#define CNT_OFF 1296128    // d_ws byte offset of per-image arrival counters

__device__ __forceinline__ unsigned rotl32(unsigned x, int r) {
  return (x << r) | (x >> (32 - r));
}

// Threefry-2x32, 20 rounds. JAX partitionable 32-bit stream for key(42):
// counter i (uint64) -> x0 = hi(i)=0, x1 = lo(i)=i; key=(0,42); bits = out0^out1
__device__ __forceinline__ unsigned threefry_bits(unsigned ctr) {
  const unsigned k0 = 0u, k1 = 42u;
  const unsigned k2 = k0 ^ k1 ^ 0x1BD11BDAu;
  unsigned x0 = 0u + k0;
  unsigned x1 = ctr + k1;
#define TF4(a,b,c,d) \
  x0 += x1; x1 = rotl32(x1,(a)); x1 ^= x0; \
  x0 += x1; x1 = rotl32(x1,(b)); x1 ^= x0; \
  x0 += x1; x1 = rotl32(x1,(c)); x1 ^= x0; \
  x0 += x1; x1 = rotl32(x1,(d)); x1 ^= x0;
  TF4(13,15,26, 6)  x0 += k1; x1 += k2 + 1u;
  TF4(17,29,16,24)  x0 += k2; x1 += k0 + 2u;
  TF4(13,15,26, 6)  x0 += k0; x1 += k1 + 3u;
  TF4(17,29,16,24)  x0 += k1; x1 += k2 + 4u;
  TF4(13,15,26, 6)  x0 += k2; x1 += k0 + 5u;
#undef TF4
  return x0 ^ x1;
}

// 256 blocks x 1024 threads. Block x labels chunk (x&7) of image (x>>3),
// then the LAST-arriving block per image runs the select phase for it.
// No grid-wide barrier; per-image device-scope atomic counter.
__global__ __launch_bounds__(NTHR) void roiheads_fused(
    const float* __restrict__ proposals,
    const float* __restrict__ gt_boxes,
    const int*   __restrict__ gt_labels,
    unsigned*    __restrict__ packed,
    unsigned char* __restrict__ midxv,
    unsigned*    __restrict__ cnt,
    float*       __restrict__ out)
{
  const int tid = threadIdx.x;
  const int lane = tid & 63;
  const int wid = tid >> 6;
  const int b = blockIdx.x >> 3;       // image
  const int c = blockIdx.x & 7;        // chunk

  __shared__ float4  sgq[GG];
  __shared__ float   sarea[GG];
  __shared__ int     slab[GG];
  __shared__ __align__(16) unsigned sp[PT];
  __shared__ unsigned hist[HB];        // pos count low16 | neg count high16
  __shared__ unsigned waveTot[NWAVE];
  __shared__ unsigned wHard[NWAVE], wTP[NWAVE], wTN[NWAVE];
  __shared__ unsigned gbufP[GCAP], gbufN[GCAP];
  __shared__ unsigned sBin[2], sAbove[2], sTheta[2], sM[2], sCnt[2];
  __shared__ unsigned sArrive;

  // ================= phase 1: label own chunk =================
  if (tid < GG) {
    float4 q = ((const float4*)gt_boxes)[(size_t)b * GG + tid];
    sgq[tid] = q;
    sarea[tid] = (q.z - q.x) * (q.w - q.y);   // same op order as reference
    slab[tid] = gt_labels[b * GG + tid];
  }
  __syncthreads();

  {
    const int t = c * NTHR + tid;
    if (t < PT) {
      float4 p = (t < PP) ? ((const float4*)proposals)[(size_t)b * PP + t]
                          : ((const float4*)gt_boxes)[(size_t)b * GG + (t - PP)];
      float area_p = (p.z - p.x) * (p.w - p.y);
      asm volatile("" : "+v"(area_p));         // block FMA contraction into sum

      float best = -1.0f;
      int bidx = 0;
      for (int g = 0; g < GG; ++g) {
        float4 q = sgq[g];
        float w = fminf(q.z, p.z) - fmaxf(q.x, p.x);
        float h = fminf(q.w, p.w) - fmaxf(q.y, p.y);
        w = fmaxf(w, 0.0f);
        h = fmaxf(h, 0.0f);
        float inter = w * h;
        asm volatile("" : "+v"(inter));        // block FMA contraction into union
        float uni = (sarea[g] + area_p) - inter;
        float iou = inter / uni;
        if (iou > best) { best = iou; bidx = g; }  // first-max == jnp argmax
      }

      int cls, m;
      if (best < 0.5f) { cls = 0; m = 0; }
      else             { cls = slab[bidx]; m = bidx; }

      unsigned bits = threefry_bits((unsigned)(b * PT + t));
      packed[(size_t)b * PT + t] = (bits >> 9) | ((unsigned)cls << 24);
      midxv[(size_t)b * PT + t] = (unsigned char)m;
    }
  }

  // ============ arrival: last block of this image proceeds ============
  __syncthreads();                     // drains all waves' stores (vmcnt(0))
  if (tid == 0) {
    __threadfence();                   // release: publish packed/midxv
    sArrive = atomicAdd(&cnt[b], 1u);
  }
  __syncthreads();
  if (sArrive != 7u) return;           // not last -> done
  __threadfence();                     // acquire: see all 8 chunks

  // ================= phase 2: select (R8 logic, verbatim) =================
  const unsigned long long laneLT = (lane == 63) ? 0x7FFFFFFFFFFFFFFFull
                                                 : ((1ull << lane) - 1ull);

  // 1: zero histogram
#pragma unroll
  for (int i = 0; i < HB / NTHR; ++i) hist[tid + i * NTHR] = 0u;
  __syncthreads();

  // 2: load keys as uint4 + histogram from registers (one fused pass)
  {
    const uint4* pk4 = (const uint4*)(packed + (size_t)b * PT);
    for (int i = tid; i < PT4; i += NTHR) {
      uint4 v = pk4[i];
      ((uint4*)sp)[i] = v;
#define H1(x) atomicAdd(&hist[((x) & 0x7FFFFFu) >> 11], ((x) >> 24) >= 1u ? 1u : 0x10000u)
      H1(v.x); H1(v.y); H1(v.z); H1(v.w);
#undef H1
    }
  }
  __syncthreads();

  // 3: block suffix-scan over per-thread 4-bin sums (packed)
  const int BPT = HB / NTHR;           // 4 bins per thread
  unsigned local = 0;
#pragma unroll
  for (int j = 0; j < BPT; ++j) local += hist[tid * BPT + j];
  unsigned suf = local;
  for (int d = 1; d < 64; d <<= 1) {
    unsigned o = __shfl_down(suf, d, 64);
    if (lane + d < 64) suf += o;
  }
  if (lane == 0) waveTot[wid] = suf;   // whole-wave sum
  __syncthreads();

  // 4: totals, caps, locate threshold bins; zero gather counters
  unsigned totAll = 0, waveAfter = 0;
#pragma unroll
  for (int w = 0; w < NWAVE; ++w) { unsigned x = waveTot[w]; totAll += x; if (w > wid) waveAfter += x; }
  unsigned num_pos = totAll & 0xFFFFu, num_neg = totAll >> 16;
  bool allP = (num_pos <= POSCAP);
  unsigned capP = allP ? num_pos : POSCAP;
  unsigned Kneg = NSEL - capP;
  bool allN = (num_neg <= Kneg);
  unsigned sumAfter = waveAfter + (suf - local);  // threads strictly after me
  {
    unsigned aP = sumAfter & 0xFFFFu, aN = sumAfter >> 16;
#pragma unroll
    for (int j = BPT - 1; j >= 0; --j) {
      unsigned hc = hist[tid * BPT + j];
      unsigned hp = hc & 0xFFFFu, hn = hc >> 16;
      if (!allP && aP < POSCAP && aP + hp >= POSCAP) { sBin[0] = tid * BPT + j; sAbove[0] = aP; }
      if (!allN && aN < Kneg   && aN + hn >= Kneg)   { sBin[1] = tid * BPT + j; sAbove[1] = aN; }
      aP += hp; aN += hn;
    }
  }
  if (tid < 2) sCnt[tid] = 0u;
  __syncthreads();

  // 5: gather members of the threshold bins
  unsigned binP = sBin[0], binN = sBin[1];
  for (int t = tid; t < PT; t += NTHR) {
    unsigned v = sp[t];
    unsigned key = v & 0x7FFFFFu;
    bool isP = (v >> 24) >= 1u;
    if (!allP && isP && (key >> 11) == binP) {
      unsigned i = atomicAdd(&sCnt[0], 1u);
      if (i < GCAP) gbufP[i] = key;
    }
    if (!allN && !isP && (key >> 11) == binN) {
      unsigned i = atomicAdd(&sCnt[1], 1u);
      if (i < GCAP) gbufN[i] = key;
    }
  }
  __syncthreads();

  // 6: exact in-bin rank resolve (wave 0: pos, wave 1: neg)
  if (wid == 0 && !allP) {
    int n = min((int)sCnt[0], GCAP);
    unsigned above = sAbove[0];
    unsigned r = POSCAP - above;       // 1-indexed rank within bin
    for (int i = lane; i < n; i += 64) {
      unsigned ki = gbufP[i];
      unsigned gt = 0, ge = 0;
      for (int j = 0; j < n; ++j) { unsigned kj = gbufP[j]; gt += (kj > ki); ge += (kj >= ki); }
      if (gt < r && ge >= r) { sTheta[0] = ki; sM[0] = POSCAP - (above + gt); }
    }
  }
  if (wid == 1 && !allN) {
    int n = min((int)sCnt[1], GCAP);
    unsigned above = sAbove[1];
    unsigned r = Kneg - above;
    for (int i = lane; i < n; i += 64) {
      unsigned ki = gbufN[i];
      unsigned gt = 0, ge = 0;
      for (int j = 0; j < n; ++j) { unsigned kj = gbufN[j]; gt += (kj > ki); ge += (kj >= ki); }
      if (gt < r && ge >= r) { sTheta[1] = ki; sM[1] = Kneg - (above + gt); }
    }
  }
  __syncthreads();

  unsigned thetaP = allP ? 0u : sTheta[0];
  unsigned mP     = allP ? 0u : sM[0];
  unsigned thetaN = allN ? 0u : sTheta[1];
  unsigned mN     = allN ? 0u : sM[1];

  // 7: pass 1 — per-wave tie/hard counts over its contiguous span (stride-1)
  const int s0 = wid * SPAN;
  unsigned hardCnt = 0, tpCnt = 0, tnCnt = 0;
#pragma unroll
  for (int step = 0; step < SPAN / 64; ++step) {
    int t = s0 + step * 64 + lane;
    bool hard = false, tp = false, tn = false;
    if (t < PT) {
      unsigned v = sp[t];
      unsigned key = v & 0x7FFFFFu;
      if ((v >> 24) >= 1u) {
        if (allP || key > thetaP) hard = true;
        else if (key == thetaP)   tp = true;
      } else {
        if (allN || key > thetaN) hard = true;
        else if (key == thetaN)   tn = true;
      }
    }
    hardCnt += __popcll(__ballot(hard));
    tpCnt   += __popcll(__ballot(tp));
    tnCnt   += __popcll(__ballot(tn));
  }
  if (lane == 0) { wHard[wid] = hardCnt; wTP[wid] = tpCnt; wTN[wid] = tnCnt; }
  __syncthreads();

  // 8: per-wave bases (ties taken in global index order -> analytic)
  unsigned tieBaseP = 0, tieBaseN = 0, posBase = 0;
  {
    unsigned tb = 0, nb = 0;
#pragma unroll
    for (int w = 0; w < NWAVE; ++w) {
      if (w == wid) { tieBaseP = tb; tieBaseN = nb; break; }
      unsigned takeP = (mP > tb) ? min(mP - tb, wTP[w]) : 0u;
      unsigned takeN = (mN > nb) ? min(mN - nb, wTN[w]) : 0u;
      posBase += wHard[w] + takeP + takeN;
      tb += wTP[w]; nb += wTN[w];
    }
  }

  // 9: pass 2 — decide + write (ballot ranks, stable index order)
  unsigned runP = tieBaseP, runN = tieBaseN, posRun = posBase;
#pragma unroll
  for (int step = 0; step < SPAN / 64; ++step) {
    int t = s0 + step * 64 + lane;
    bool hard = false, tp = false, tn = false;
    unsigned cls = 0;
    if (t < PT) {
      unsigned v = sp[t];
      unsigned key = v & 0x7FFFFFu;
      cls = v >> 24;
      if (cls >= 1u) {
        if (allP || key > thetaP) hard = true;
        else if (key == thetaP)   tp = true;
      } else {
        if (allN || key > thetaN) hard = true;
        else if (key == thetaN)   tn = true;
      }
    }
    unsigned long long mtp = __ballot(tp);
    unsigned long long mtn = __ballot(tn);
    bool sel = hard
             | (tp && (runP + __popcll(mtp & laneLT)) < mP)
             | (tn && (runN + __popcll(mtn & laneLT)) < mN);
    unsigned long long msel = __ballot(sel);

    if (sel) {
      unsigned pos = posRun + __popcll(msel & laneLT);
      float4 p = (t < PP) ? ((const float4*)proposals)[(size_t)b * PP + t]
                          : ((const float4*)gt_boxes)[(size_t)b * GG + (t - PP)];
      int m = midxv[(size_t)b * PT + t];
      float4 gq = ((const float4*)gt_boxes)[(size_t)b * GG + m];

      size_t o1 = (size_t)b * NSEL + pos;
      out[o1 * 4 + 0] = p.x;
      out[o1 * 4 + 1] = p.y;
      out[o1 * 4 + 2] = p.z;
      out[o1 * 4 + 3] = p.w;
      out[OFF_LAB + o1] = (float)cls;

      float pw = p.z - p.x, ph = p.w - p.y;
      float px = p.x + 0.5f * pw, py = p.y + 0.5f * ph;
      float gw = gq.z - gq.x, gh = gq.w - gq.y;
      float gx = gq.x + 0.5f * gw, gy = gq.y + 0.5f * gh;
      size_t o2 = OFF_REG + o1 * 4;
      out[o2 + 0] = 10.0f * (gx - px) / pw;
      out[o2 + 1] = 10.0f * (gy - py) / ph;
      out[o2 + 2] = 5.0f * logf(gw / pw);
      out[o2 + 3] = 5.0f * logf(gh / ph);
    }

    runP += __popcll(mtp);
    runN += __popcll(mtn);
    posRun += __popcll(msel);
  }
}

extern "C" void kernel_launch(void* const* d_in, const int* in_sizes, int n_in,
                              void* d_out, int out_size, void* d_ws, size_t ws_size,
                              hipStream_t stream) {
  const float* proposals = (const float*)d_in[0];
  const float* gt_boxes  = (const float*)d_in[1];
  const int*   gt_labels = (const int*)d_in[2];
  float* out = (float*)d_out;

  unsigned* packed = (unsigned*)d_ws;
  unsigned char* midxv = (unsigned char*)d_ws + (size_t)BB * PT * sizeof(unsigned);
  unsigned* cnt = (unsigned*)((char*)d_ws + CNT_OFF);

  hipMemsetAsync(cnt, 0, BB * sizeof(unsigned), stream);   // arrival counters
  roiheads_fused<<<BB * 8, NTHR, 0, stream>>>(proposals, gt_boxes, gt_labels,
                                              packed, midxv, cnt, out);
}

// Round 11
// 45.888 us; speedup vs baseline: 3.5420x; 1.8800x over previous
//
#include <hip/hip_runtime.h>

#define BB 32
#define PP 8000
#define GG 100
#define PT 8100            // P + G
#define NSEL 512
#define POSCAP 128
#define OFF_LAB 65536      // 32*512*4
#define OFF_REG 81920      // OFF_LAB + 32*512
#define NT1 256
#define NT2 1024           // select: 16 waves
#define NWAVE 16
#define SPAN 512           // span per wave; lane owns 8 consecutive keys
#define KPL 8              // keys per lane (SPAN/64)
#define HB 4096            // histogram bins (top 12 of 23 key bits)
#define GCAP 512           // gather buffer cap per group

__device__ __forceinline__ unsigned rotl32(unsigned x, int r) {
  return (x << r) | (x >> (32 - r));
}

// Threefry-2x32, 20 rounds. JAX partitionable 32-bit stream for key(42):
// counter i (uint64) -> x0 = hi(i)=0, x1 = lo(i)=i; key=(0,42); bits = out0^out1
__device__ __forceinline__ unsigned threefry_bits(unsigned ctr) {
  const unsigned k0 = 0u, k1 = 42u;
  const unsigned k2 = k0 ^ k1 ^ 0x1BD11BDAu;
  unsigned x0 = 0u + k0;
  unsigned x1 = ctr + k1;
#define TF4(a,b,c,d) \
  x0 += x1; x1 = rotl32(x1,(a)); x1 ^= x0; \
  x0 += x1; x1 = rotl32(x1,(b)); x1 ^= x0; \
  x0 += x1; x1 = rotl32(x1,(c)); x1 ^= x0; \
  x0 += x1; x1 = rotl32(x1,(d)); x1 ^= x0;
  TF4(13,15,26, 6)  x0 += k1; x1 += k2 + 1u;
  TF4(17,29,16,24)  x0 += k2; x1 += k0 + 2u;
  TF4(13,15,26, 6)  x0 += k0; x1 += k1 + 3u;
  TF4(17,29,16,24)  x0 += k1; x1 += k2 + 4u;
  TF4(13,15,26, 6)  x0 += k2; x1 += k0 + 5u;
#undef TF4
  return x0 ^ x1;
}

// Kernel 1: per (b,t): IoU argmax over G gts -> cls, midx, threefry key.
__global__ __launch_bounds__(NT1) void label_kernel(
    const float* __restrict__ proposals,
    const float* __restrict__ gt_boxes,
    const int*   __restrict__ gt_labels,
    unsigned*    __restrict__ packed,
    unsigned char* __restrict__ midxv)
{
  const int b = blockIdx.y;
  const int t = blockIdx.x * NT1 + threadIdx.x;

  __shared__ float sgx[GG], sgy[GG], sgX[GG], sgY[GG], sarea[GG];
  __shared__ int   slab[GG];
  if (threadIdx.x < GG) {
    int g = threadIdx.x;
    float4 q = ((const float4*)gt_boxes)[(size_t)b * GG + g];
    sgx[g] = q.x; sgy[g] = q.y; sgX[g] = q.z; sgY[g] = q.w;
    sarea[g] = (q.z - q.x) * (q.w - q.y);  // same op order as reference
    slab[g] = gt_labels[b * GG + g];
  }
  __syncthreads();
  if (t >= PT) return;

  float4 p = (t < PP) ? ((const float4*)proposals)[(size_t)b * PP + t]
                      : ((const float4*)gt_boxes)[(size_t)b * GG + (t - PP)];
  float area_p = (p.z - p.x) * (p.w - p.y);
  asm volatile("" : "+v"(area_p));         // block FMA contraction into sum

  float best = -1.0f;
  int bidx = 0;
  for (int g = 0; g < GG; ++g) {
    float w = fminf(sgX[g], p.z) - fmaxf(sgx[g], p.x);
    float h = fminf(sgY[g], p.w) - fmaxf(sgy[g], p.y);
    w = fmaxf(w, 0.0f);
    h = fmaxf(h, 0.0f);
    float inter = w * h;
    asm volatile("" : "+v"(inter));        // block FMA contraction into union
    float uni = (sarea[g] + area_p) - inter;
    float iou = inter / uni;
    if (iou > best) { best = iou; bidx = g; }   // first-max == jnp argmax
  }

  int cls, m;
  if (best < 0.5f) { cls = 0; m = 0; }
  else             { cls = slab[bidx]; m = bidx; }

  unsigned bits = threefry_bits((unsigned)(b * PT + t));
  packed[(size_t)b * PT + t] = (bits >> 9) | ((unsigned)cls << 24);
  midxv[(size_t)b * PT + t] = (unsigned char)m;
}

// Kernel 2: one block (16 waves) per image. Keys live in REGISTERS (8/lane,
// lane-major span order); LDS only for histogram + small arrays. 7 barriers.
__global__ __launch_bounds__(NT2) void select_kernel(
    const float*    __restrict__ proposals,
    const float*    __restrict__ gt_boxes,
    const unsigned* __restrict__ packed,
    const unsigned char* __restrict__ midxv,
    float* __restrict__ out)
{
  const int b = blockIdx.x;
  const int tid = threadIdx.x;
  const int lane = tid & 63;
  const int wid = tid >> 6;
  const unsigned long long laneLT = (1ull << lane) - 1ull;  // lanes strictly below

  __shared__ unsigned hist[HB];        // pos count low16 | neg count high16
  __shared__ unsigned waveTot[NWAVE];
  __shared__ unsigned wHard[NWAVE], wTP[NWAVE], wTN[NWAVE];
  __shared__ unsigned gbufP[GCAP], gbufN[GCAP];
  __shared__ unsigned sBin[2], sAbove[2], sTheta[2], sM[2], sCnt[2];

  // lane owns elements t = s0 + lane*8 + j (lane-major index order)
  const int s0 = wid * SPAN;
  const int tBase = s0 + lane * KPL;
  unsigned k[KPL];
  {
    const uint4* pk4 = (const uint4*)(packed + (size_t)b * PT);
    uint4 va = pk4[(s0 >> 2) + lane * 2];
    uint4 vb = pk4[(s0 >> 2) + lane * 2 + 1];
    k[0]=va.x; k[1]=va.y; k[2]=va.z; k[3]=va.w;
    k[4]=vb.x; k[5]=vb.y; k[6]=vb.z; k[7]=vb.w;
  }

  // zero hist
#pragma unroll
  for (int i = 0; i < HB / NT2; ++i) hist[tid + i * NT2] = 0u;
  __syncthreads();                     // B1

  // histogram on top 12 bits of the 23-bit key (from registers)
#pragma unroll
  for (int j = 0; j < KPL; ++j) {
    if (tBase + j < PT)
      atomicAdd(&hist[(k[j] & 0x7FFFFFu) >> 11],
                (k[j] >> 24) >= 1u ? 1u : 0x10000u);
  }
  __syncthreads();                     // B2

  // block suffix-scan over per-thread 4-bin sums (packed)
  const int BPT = HB / NT2;            // 4 bins per thread
  unsigned local = 0;
#pragma unroll
  for (int j = 0; j < BPT; ++j) local += hist[tid * BPT + j];
  unsigned suf = local;
  for (int d = 1; d < 64; d <<= 1) {
    unsigned o = __shfl_down(suf, d, 64);
    if (lane + d < 64) suf += o;
  }
  if (lane == 0) waveTot[wid] = suf;   // whole-wave sum
  if (tid < 2) sCnt[tid] = 0u;
  __syncthreads();                     // B3

  // totals, caps, locate threshold bins
  unsigned totAll = 0, waveAfter = 0;
#pragma unroll
  for (int w = 0; w < NWAVE; ++w) { unsigned x = waveTot[w]; totAll += x; if (w > wid) waveAfter += x; }
  unsigned num_pos = totAll & 0xFFFFu, num_neg = totAll >> 16;
  bool allP = (num_pos <= POSCAP);
  unsigned capP = allP ? num_pos : POSCAP;
  unsigned Kneg = NSEL - capP;
  bool allN = (num_neg <= Kneg);
  unsigned sumAfter = waveAfter + (suf - local);  // threads strictly after me
  {
    unsigned aP = sumAfter & 0xFFFFu, aN = sumAfter >> 16;
#pragma unroll
    for (int j = BPT - 1; j >= 0; --j) {
      unsigned hc = hist[tid * BPT + j];
      unsigned hp = hc & 0xFFFFu, hn = hc >> 16;
      if (!allP && aP < POSCAP && aP + hp >= POSCAP) { sBin[0] = tid * BPT + j; sAbove[0] = aP; }
      if (!allN && aN < Kneg   && aN + hn >= Kneg)   { sBin[1] = tid * BPT + j; sAbove[1] = aN; }
      aP += hp; aN += hn;
    }
  }
  __syncthreads();                     // B4

  // gather members of the threshold bins (from registers)
  unsigned binP = sBin[0], binN = sBin[1];
#pragma unroll
  for (int j = 0; j < KPL; ++j) {
    if (tBase + j < PT) {
      unsigned key = k[j] & 0x7FFFFFu;
      bool isP = (k[j] >> 24) >= 1u;
      if (!allP && isP && (key >> 11) == binP) {
        unsigned i = atomicAdd(&sCnt[0], 1u);
        if (i < GCAP) gbufP[i] = key;
      }
      if (!allN && !isP && (key >> 11) == binN) {
        unsigned i = atomicAdd(&sCnt[1], 1u);
        if (i < GCAP) gbufN[i] = key;
      }
    }
  }
  __syncthreads();                     // B5

  // exact in-bin rank resolve (wave 0: pos, wave 1: neg)
  if (wid == 0 && !allP) {
    int n = min((int)sCnt[0], GCAP);
    unsigned above = sAbove[0];
    unsigned r = POSCAP - above;       // 1-indexed rank within bin
    for (int i = lane; i < n; i += 64) {
      unsigned ki = gbufP[i];
      unsigned gt = 0, ge = 0;
      for (int j = 0; j < n; ++j) { unsigned kj = gbufP[j]; gt += (kj > ki); ge += (kj >= ki); }
      if (gt < r && ge >= r) { sTheta[0] = ki; sM[0] = POSCAP - (above + gt); }
    }
  }
  if (wid == 1 && !allN) {
    int n = min((int)sCnt[1], GCAP);
    unsigned above = sAbove[1];
    unsigned r = Kneg - above;
    for (int i = lane; i < n; i += 64) {
      unsigned ki = gbufN[i];
      unsigned gt = 0, ge = 0;
      for (int j = 0; j < n; ++j) { unsigned kj = gbufN[j]; gt += (kj > ki); ge += (kj >= ki); }
      if (gt < r && ge >= r) { sTheta[1] = ki; sM[1] = Kneg - (above + gt); }
    }
  }
  __syncthreads();                     // B6

  unsigned thetaP = allP ? 0u : sTheta[0];
  unsigned mP     = allP ? 0u : sM[0];
  unsigned thetaN = allN ? 0u : sTheta[1];
  unsigned mN     = allN ? 0u : sM[1];

  // pass 1: per-lane 8-bit flag masks + wave totals via ballots
  unsigned myHard = 0, myTP = 0, myTN = 0;
#pragma unroll
  for (int j = 0; j < KPL; ++j) {
    if (tBase + j < PT) {
      unsigned key = k[j] & 0x7FFFFFu;
      if ((k[j] >> 24) >= 1u) {
        if (allP || key > thetaP) myHard |= 1u << j;
        else if (key == thetaP)   myTP |= 1u << j;
      } else {
        if (allN || key > thetaN) myHard |= 1u << j;
        else if (key == thetaN)   myTN |= 1u << j;
      }
    }
  }
  unsigned hardCnt = 0, tpCnt = 0, tnCnt = 0;
#pragma unroll
  for (int j = 0; j < KPL; ++j) {
    hardCnt += __popcll(__ballot((myHard >> j) & 1u));
    tpCnt   += __popcll(__ballot((myTP   >> j) & 1u));
    tnCnt   += __popcll(__ballot((myTN   >> j) & 1u));
  }
  if (lane == 0) { wHard[wid] = hardCnt; wTP[wid] = tpCnt; wTN[wid] = tnCnt; }
  __syncthreads();                     // B7

  // per-wave bases (ties taken in global index order -> analytic)
  unsigned tieBaseP = 0, tieBaseN = 0, posBase = 0;
  {
    unsigned tb = 0, nb = 0;
#pragma unroll
    for (int w = 0; w < NWAVE; ++w) {
      if (w == wid) { tieBaseP = tb; tieBaseN = nb; break; }
      unsigned takeP = (mP > tb) ? min(mP - tb, wTP[w]) : 0u;
      unsigned takeN = (mN > nb) ? min(mN - nb, wTN[w]) : 0u;
      posBase += wHard[w] + takeP + takeN;
      tb += wTP[w]; nb += wTN[w];
    }
  }

  // pass 2: tie ranks, selection, positions — lane-major index order.
  // rank(lane,j) = base + sum_j' popc(mask[j'] & laneLT) + (#own flags j'<j)
  {
    unsigned long long mtp[KPL], mtn[KPL];
#pragma unroll
    for (int j = 0; j < KPL; ++j) {
      mtp[j] = __ballot((myTP >> j) & 1u);
      mtn[j] = __ballot((myTN >> j) & 1u);
    }
    unsigned basTP = tieBaseP, basTN = tieBaseN;
#pragma unroll
    for (int j = 0; j < KPL; ++j) {
      basTP += __popcll(mtp[j] & laneLT);
      basTN += __popcll(mtn[j] & laneLT);
    }
    unsigned mySel = 0, prefTP = 0, prefTN = 0;
#pragma unroll
    for (int j = 0; j < KPL; ++j) {
      bool s = (myHard >> j) & 1u;
      if ((myTP >> j) & 1u) { s = (basTP + prefTP) < mP; prefTP++; }
      if ((myTN >> j) & 1u) { s = (basTN + prefTN) < mN; prefTN++; }
      if (s) mySel |= 1u << j;
    }
    unsigned posAcc = posBase;
#pragma unroll
    for (int j = 0; j < KPL; ++j)
      posAcc += __popcll(__ballot((mySel >> j) & 1u) & laneLT);

    unsigned prefSel = 0;
#pragma unroll
    for (int j = 0; j < KPL; ++j) {
      if ((mySel >> j) & 1u) {
        int t = tBase + j;
        unsigned cls = k[j] >> 24;
        unsigned pos = posAcc + prefSel;
        prefSel++;

        float4 p = (t < PP) ? ((const float4*)proposals)[(size_t)b * PP + t]
                            : ((const float4*)gt_boxes)[(size_t)b * GG + (t - PP)];
        int m = midxv[(size_t)b * PT + t];
        float4 gq = ((const float4*)gt_boxes)[(size_t)b * GG + m];

        size_t o1 = (size_t)b * NSEL + pos;
        out[o1 * 4 + 0] = p.x;
        out[o1 * 4 + 1] = p.y;
        out[o1 * 4 + 2] = p.z;
        out[o1 * 4 + 3] = p.w;
        out[OFF_LAB + o1] = (float)cls;

        float pw = p.z - p.x, ph = p.w - p.y;
        float px = p.x + 0.5f * pw, py = p.y + 0.5f * ph;
        float gw = gq.z - gq.x, gh = gq.w - gq.y;
        float gx = gq.x + 0.5f * gw, gy = gq.y + 0.5f * gh;
        size_t o2 = OFF_REG + o1 * 4;
        out[o2 + 0] = 10.0f * (gx - px) / pw;
        out[o2 + 1] = 10.0f * (gy - py) / ph;
        out[o2 + 2] = 5.0f * logf(gw / pw);
        out[o2 + 3] = 5.0f * logf(gh / ph);
      }
    }
  }
}

extern "C" void kernel_launch(void* const* d_in, const int* in_sizes, int n_in,
                              void* d_out, int out_size, void* d_ws, size_t ws_size,
                              hipStream_t stream) {
  const float* proposals = (const float*)d_in[0];
  const float* gt_boxes  = (const float*)d_in[1];
  const int*   gt_labels = (const int*)d_in[2];
  float* out = (float*)d_out;

  unsigned* packed = (unsigned*)d_ws;
  unsigned char* midxv = (unsigned char*)d_ws + (size_t)BB * PT * sizeof(unsigned);

  dim3 g1((PT + NT1 - 1) / NT1, BB);
  label_kernel<<<g1, NT1, 0, stream>>>(proposals, gt_boxes, gt_labels, packed, midxv);
  select_kernel<<<BB, NT2, 0, stream>>>(proposals, gt_boxes, packed, midxv, out);
}

// Round 12
// 43.700 us; speedup vs baseline: 3.7194x; 1.0501x over previous
//
#include <hip/hip_runtime.h>

#define BB 32
#define PP 8000
#define GG 100
#define PT 8100            // P + G
#define NSEL 512
#define POSCAP 128
#define OFF_LAB 65536      // 32*512*4
#define OFF_REG 81920      // OFF_LAB + 32*512
#define NT1 256
#define NT2 1024           // select: 16 waves
#define NWAVE 16
#define SPAN 512           // span per wave; lane owns 8 consecutive keys
#define KPL 8              // keys per lane (SPAN/64)
#define HB 4096            // histogram bins (top 12 of 23 key bits)
#define GCAP 512           // gather buffer cap per group

__device__ __forceinline__ unsigned rotl32(unsigned x, int r) {
  return (x << r) | (x >> (32 - r));
}

// Threefry-2x32, 20 rounds. JAX partitionable 32-bit stream for key(42):
// counter i (uint64) -> x0 = hi(i)=0, x1 = lo(i)=i; key=(0,42); bits = out0^out1
__device__ __forceinline__ unsigned threefry_bits(unsigned ctr) {
  const unsigned k0 = 0u, k1 = 42u;
  const unsigned k2 = k0 ^ k1 ^ 0x1BD11BDAu;
  unsigned x0 = 0u + k0;
  unsigned x1 = ctr + k1;
#define TF4(a,b,c,d) \
  x0 += x1; x1 = rotl32(x1,(a)); x1 ^= x0; \
  x0 += x1; x1 = rotl32(x1,(b)); x1 ^= x0; \
  x0 += x1; x1 = rotl32(x1,(c)); x1 ^= x0; \
  x0 += x1; x1 = rotl32(x1,(d)); x1 ^= x0;
  TF4(13,15,26, 6)  x0 += k1; x1 += k2 + 1u;
  TF4(17,29,16,24)  x0 += k2; x1 += k0 + 2u;
  TF4(13,15,26, 6)  x0 += k0; x1 += k1 + 3u;
  TF4(17,29,16,24)  x0 += k1; x1 += k2 + 4u;
  TF4(13,15,26, 6)  x0 += k2; x1 += k0 + 5u;
#undef TF4
  return x0 ^ x1;
}

// Kernel 1: per (b,t): IoU argmax over G gts -> cls, midx, threefry key.
// gt staged as float4 (1 ds_read_b128 + 1 ds_read_b32 per gt, broadcast).
__global__ __launch_bounds__(NT1) void label_kernel(
    const float* __restrict__ proposals,
    const float* __restrict__ gt_boxes,
    const int*   __restrict__ gt_labels,
    unsigned*    __restrict__ packed,
    unsigned char* __restrict__ midxv)
{
  const int b = blockIdx.y;
  const int t = blockIdx.x * NT1 + threadIdx.x;

  __shared__ float4 sgq[GG];
  __shared__ float  sarea[GG];
  __shared__ int    slab[GG];
  if (threadIdx.x < GG) {
    int g = threadIdx.x;
    float4 q = ((const float4*)gt_boxes)[(size_t)b * GG + g];
    sgq[g] = q;
    sarea[g] = (q.z - q.x) * (q.w - q.y);  // same op order as reference
    slab[g] = gt_labels[b * GG + g];
  }
  __syncthreads();
  if (t >= PT) return;

  float4 p = (t < PP) ? ((const float4*)proposals)[(size_t)b * PP + t]
                      : ((const float4*)gt_boxes)[(size_t)b * GG + (t - PP)];
  float area_p = (p.z - p.x) * (p.w - p.y);
  asm volatile("" : "+v"(area_p));         // block FMA contraction into sum

  float best = -1.0f;
  int bidx = 0;
#pragma unroll 4
  for (int g = 0; g < GG; ++g) {
    float4 q = sgq[g];
    float w = fminf(q.z, p.z) - fmaxf(q.x, p.x);
    float h = fminf(q.w, p.w) - fmaxf(q.y, p.y);
    w = fmaxf(w, 0.0f);
    h = fmaxf(h, 0.0f);
    float inter = w * h;
    asm volatile("" : "+v"(inter));        // block FMA contraction into union
    float uni = (sarea[g] + area_p) - inter;
    float iou = inter / uni;
    if (iou > best) { best = iou; bidx = g; }   // first-max == jnp argmax
  }

  int cls, m;
  if (best < 0.5f) { cls = 0; m = 0; }
  else             { cls = slab[bidx]; m = bidx; }

  unsigned bits = threefry_bits((unsigned)(b * PT + t));
  packed[(size_t)b * PT + t] = (bits >> 9) | ((unsigned)cls << 24);
  midxv[(size_t)b * PT + t] = (unsigned char)m;
}

// Kernel 2: one block (16 waves) per image. Keys in registers (8/lane);
// epilogue gathers batched into independent stages to hide HBM/L2 latency.
__global__ __launch_bounds__(NT2) void select_kernel(
    const float*    __restrict__ proposals,
    const float*    __restrict__ gt_boxes,
    const unsigned* __restrict__ packed,
    const unsigned char* __restrict__ midxv,
    float* __restrict__ out)
{
  const int b = blockIdx.x;
  const int tid = threadIdx.x;
  const int lane = tid & 63;
  const int wid = tid >> 6;
  const unsigned long long laneLT = (1ull << lane) - 1ull;  // lanes strictly below

  __shared__ unsigned hist[HB];        // pos count low16 | neg count high16
  __shared__ unsigned waveTot[NWAVE];
  __shared__ unsigned wHard[NWAVE], wTP[NWAVE], wTN[NWAVE];
  __shared__ unsigned gbufP[GCAP], gbufN[GCAP];
  __shared__ unsigned sBin[2], sAbove[2], sTheta[2], sM[2], sCnt[2];

  // lane owns elements t = s0 + lane*8 + j (lane-major index order)
  const int s0 = wid * SPAN;
  const int tBase = s0 + lane * KPL;
  unsigned k[KPL];
  {
    const uint4* pk4 = (const uint4*)(packed + (size_t)b * PT);
    uint4 va = pk4[(s0 >> 2) + lane * 2];
    uint4 vb = pk4[(s0 >> 2) + lane * 2 + 1];
    k[0]=va.x; k[1]=va.y; k[2]=va.z; k[3]=va.w;
    k[4]=vb.x; k[5]=vb.y; k[6]=vb.z; k[7]=vb.w;
  }

  // zero hist
#pragma unroll
  for (int i = 0; i < HB / NT2; ++i) hist[tid + i * NT2] = 0u;
  __syncthreads();                     // B1

  // histogram on top 12 bits of the 23-bit key (from registers)
#pragma unroll
  for (int j = 0; j < KPL; ++j) {
    if (tBase + j < PT)
      atomicAdd(&hist[(k[j] & 0x7FFFFFu) >> 11],
                (k[j] >> 24) >= 1u ? 1u : 0x10000u);
  }
  __syncthreads();                     // B2

  // block suffix-scan over per-thread 4-bin sums (packed)
  const int BPT = HB / NT2;            // 4 bins per thread
  unsigned local = 0;
#pragma unroll
  for (int j = 0; j < BPT; ++j) local += hist[tid * BPT + j];
  unsigned suf = local;
  for (int d = 1; d < 64; d <<= 1) {
    unsigned o = __shfl_down(suf, d, 64);
    if (lane + d < 64) suf += o;
  }
  if (lane == 0) waveTot[wid] = suf;   // whole-wave sum
  if (tid < 2) sCnt[tid] = 0u;
  __syncthreads();                     // B3

  // totals, caps, locate threshold bins
  unsigned totAll = 0, waveAfter = 0;
#pragma unroll
  for (int w = 0; w < NWAVE; ++w) { unsigned x = waveTot[w]; totAll += x; if (w > wid) waveAfter += x; }
  unsigned num_pos = totAll & 0xFFFFu, num_neg = totAll >> 16;
  bool allP = (num_pos <= POSCAP);
  unsigned capP = allP ? num_pos : POSCAP;
  unsigned Kneg = NSEL - capP;
  bool allN = (num_neg <= Kneg);
  unsigned sumAfter = waveAfter + (suf - local);  // threads strictly after me
  {
    unsigned aP = sumAfter & 0xFFFFu, aN = sumAfter >> 16;
#pragma unroll
    for (int j = BPT - 1; j >= 0; --j) {
      unsigned hc = hist[tid * BPT + j];
      unsigned hp = hc & 0xFFFFu, hn = hc >> 16;
      if (!allP && aP < POSCAP && aP + hp >= POSCAP) { sBin[0] = tid * BPT + j; sAbove[0] = aP; }
      if (!allN && aN < Kneg   && aN + hn >= Kneg)   { sBin[1] = tid * BPT + j; sAbove[1] = aN; }
      aP += hp; aN += hn;
    }
  }
  __syncthreads();                     // B4

  // gather members of the threshold bins (from registers)
  unsigned binP = sBin[0], binN = sBin[1];
#pragma unroll
  for (int j = 0; j < KPL; ++j) {
    if (tBase + j < PT) {
      unsigned key = k[j] & 0x7FFFFFu;
      bool isP = (k[j] >> 24) >= 1u;
      if (!allP && isP && (key >> 11) == binP) {
        unsigned i = atomicAdd(&sCnt[0], 1u);
        if (i < GCAP) gbufP[i] = key;
      }
      if (!allN && !isP && (key >> 11) == binN) {
        unsigned i = atomicAdd(&sCnt[1], 1u);
        if (i < GCAP) gbufN[i] = key;
      }
    }
  }
  __syncthreads();                     // B5

  // exact in-bin rank resolve (wave 0: pos, wave 1: neg)
  if (wid == 0 && !allP) {
    int n = min((int)sCnt[0], GCAP);
    unsigned above = sAbove[0];
    unsigned r = POSCAP - above;       // 1-indexed rank within bin
    for (int i = lane; i < n; i += 64) {
      unsigned ki = gbufP[i];
      unsigned gt = 0, ge = 0;
      for (int j = 0; j < n; ++j) { unsigned kj = gbufP[j]; gt += (kj > ki); ge += (kj >= ki); }
      if (gt < r && ge >= r) { sTheta[0] = ki; sM[0] = POSCAP - (above + gt); }
    }
  }
  if (wid == 1 && !allN) {
    int n = min((int)sCnt[1], GCAP);
    unsigned above = sAbove[1];
    unsigned r = Kneg - above;
    for (int i = lane; i < n; i += 64) {
      unsigned ki = gbufN[i];
      unsigned gt = 0, ge = 0;
      for (int j = 0; j < n; ++j) { unsigned kj = gbufN[j]; gt += (kj > ki); ge += (kj >= ki); }
      if (gt < r && ge >= r) { sTheta[1] = ki; sM[1] = Kneg - (above + gt); }
    }
  }
  __syncthreads();                     // B6

  unsigned thetaP = allP ? 0u : sTheta[0];
  unsigned mP     = allP ? 0u : sM[0];
  unsigned thetaN = allN ? 0u : sTheta[1];
  unsigned mN     = allN ? 0u : sM[1];

  // pass 1: per-lane 8-bit flag masks + wave totals via ballots
  unsigned myHard = 0, myTP = 0, myTN = 0;
#pragma unroll
  for (int j = 0; j < KPL; ++j) {
    if (tBase + j < PT) {
      unsigned key = k[j] & 0x7FFFFFu;
      if ((k[j] >> 24) >= 1u) {
        if (allP || key > thetaP) myHard |= 1u << j;
        else if (key == thetaP)   myTP |= 1u << j;
      } else {
        if (allN || key > thetaN) myHard |= 1u << j;
        else if (key == thetaN)   myTN |= 1u << j;
      }
    }
  }
  unsigned hardCnt = 0, tpCnt = 0, tnCnt = 0;
#pragma unroll
  for (int j = 0; j < KPL; ++j) {
    hardCnt += __popcll(__ballot((myHard >> j) & 1u));
    tpCnt   += __popcll(__ballot((myTP   >> j) & 1u));
    tnCnt   += __popcll(__ballot((myTN   >> j) & 1u));
  }
  if (lane == 0) { wHard[wid] = hardCnt; wTP[wid] = tpCnt; wTN[wid] = tnCnt; }
  __syncthreads();                     // B7

  // per-wave bases (ties taken in global index order -> analytic)
  unsigned tieBaseP = 0, tieBaseN = 0, posBase = 0;
  {
    unsigned tb = 0, nb = 0;
#pragma unroll
    for (int w = 0; w < NWAVE; ++w) {
      if (w == wid) { tieBaseP = tb; tieBaseN = nb; break; }
      unsigned takeP = (mP > tb) ? min(mP - tb, wTP[w]) : 0u;
      unsigned takeN = (mN > nb) ? min(mN - nb, wTN[w]) : 0u;
      posBase += wHard[w] + takeP + takeN;
      tb += wTP[w]; nb += wTN[w];
    }
  }

  // pass 2: tie ranks + selection + positions, then BATCHED epilogue gathers.
  {
    unsigned long long mtp[KPL], mtn[KPL];
#pragma unroll
    for (int j = 0; j < KPL; ++j) {
      mtp[j] = __ballot((myTP >> j) & 1u);
      mtn[j] = __ballot((myTN >> j) & 1u);
    }
    unsigned basTP = tieBaseP, basTN = tieBaseN;
#pragma unroll
    for (int j = 0; j < KPL; ++j) {
      basTP += __popcll(mtp[j] & laneLT);
      basTN += __popcll(mtn[j] & laneLT);
    }
    unsigned mySel = 0, prefTP = 0, prefTN = 0;
#pragma unroll
    for (int j = 0; j < KPL; ++j) {
      bool s = (myHard >> j) & 1u;
      if ((myTP >> j) & 1u) { s = (basTP + prefTP) < mP; prefTP++; }
      if ((myTN >> j) & 1u) { s = (basTN + prefTN) < mN; prefTN++; }
      if (s) mySel |= 1u << j;
    }
    unsigned posAcc = posBase;
#pragma unroll
    for (int j = 0; j < KPL; ++j)
      posAcc += __popcll(__ballot((mySel >> j) & 1u) & laneLT);

    // positions per selected j (static indexing throughout)
    unsigned posj[KPL];
    {
      unsigned prefSel = 0;
#pragma unroll
      for (int j = 0; j < KPL; ++j) {
        posj[j] = posAcc + prefSel;
        if ((mySel >> j) & 1u) prefSel++;
      }
    }

    // stage 1: independent loads (proposal box + match idx) for all selected
    float4 pj[KPL];
    int    mj[KPL];
#pragma unroll
    for (int j = 0; j < KPL; ++j) {
      if ((mySel >> j) & 1u) {
        int t = tBase + j;
        pj[j] = (t < PP) ? ((const float4*)proposals)[(size_t)b * PP + t]
                         : ((const float4*)gt_boxes)[(size_t)b * GG + (t - PP)];
        mj[j] = midxv[(size_t)b * PT + t];
      }
    }
    // stage 2: dependent gt-box loads
    float4 gqj[KPL];
#pragma unroll
    for (int j = 0; j < KPL; ++j) {
      if ((mySel >> j) & 1u)
        gqj[j] = ((const float4*)gt_boxes)[(size_t)b * GG + mj[j]];
    }
    // stage 3: compute + store
#pragma unroll
    for (int j = 0; j < KPL; ++j) {
      if ((mySel >> j) & 1u) {
        unsigned cls = k[j] >> 24;
        float4 p = pj[j];
        float4 gq = gqj[j];
        size_t o1 = (size_t)b * NSEL + posj[j];
        out[o1 * 4 + 0] = p.x;
        out[o1 * 4 + 1] = p.y;
        out[o1 * 4 + 2] = p.z;
        out[o1 * 4 + 3] = p.w;
        out[OFF_LAB + o1] = (float)cls;

        float pw = p.z - p.x, ph = p.w - p.y;
        float px = p.x + 0.5f * pw, py = p.y + 0.5f * ph;
        float gw = gq.z - gq.x, gh = gq.w - gq.y;
        float gx = gq.x + 0.5f * gw, gy = gq.y + 0.5f * gh;
        size_t o2 = OFF_REG + o1 * 4;
        out[o2 + 0] = 10.0f * (gx - px) / pw;
        out[o2 + 1] = 10.0f * (gy - py) / ph;
        out[o2 + 2] = 5.0f * logf(gw / pw);
        out[o2 + 3] = 5.0f * logf(gh / ph);
      }
    }
  }
}

extern "C" void kernel_launch(void* const* d_in, const int* in_sizes, int n_in,
                              void* d_out, int out_size, void* d_ws, size_t ws_size,
                              hipStream_t stream) {
  const float* proposals = (const float*)d_in[0];
  const float* gt_boxes  = (const float*)d_in[1];
  const int*   gt_labels = (const int*)d_in[2];
  float* out = (float*)d_out;

  unsigned* packed = (unsigned*)d_ws;
  unsigned char* midxv = (unsigned char*)d_ws + (size_t)BB * PT * sizeof(unsigned);

  dim3 g1((PT + NT1 - 1) / NT1, BB);
  label_kernel<<<g1, NT1, 0, stream>>>(proposals, gt_boxes, gt_labels, packed, midxv);
  select_kernel<<<BB, NT2, 0, stream>>>(proposals, gt_boxes, packed, midxv, out);
}